// Round 10
// baseline (175.170 us; speedup 1.0000x reference)
//
#include <hip/hip_runtime.h>
#include <hip/hip_bf16.h>

// Problem constants
#define B_   16
#define C_   256
#define T_   2048
#define PS   12
#define NNEG 15
#define OFFS 16
#define COPIES 16
#define NPRED 6225408           // sum_i (2032-i)*256
#define NLAB  389088

using bf16 = __hip_bfloat16;
typedef __attribute__((ext_vector_type(4))) float f32x4;
typedef __attribute__((ext_vector_type(8))) short bf16x8;

#define GLL(src, dst)                                                        \
    __builtin_amdgcn_global_load_lds(                                        \
        (const __attribute__((address_space(1))) void*)(src),                \
        (__attribute__((address_space(3))) void*)(dst), 16, 0, 0)

// ---------------------------------------------------------------- transpose z
// z[b][c][t] f32  ->  zT[b][t][c] bf16
__global__ __launch_bounds__(256) void transpose_z(const float* __restrict__ z,
                                                   bf16* __restrict__ zT) {
    __shared__ float tile[32][33];
    int t0 = blockIdx.x * 32, c0 = blockIdx.y * 32, b = blockIdx.z;
    int col = threadIdx.x & 31, r = threadIdx.x >> 5;
    for (int rr = 0; rr < 4; ++rr) {
        int row = r + rr * 8;
        tile[row][col] = z[(size_t)(b * C_ + c0 + row) * T_ + t0 + col];
    }
    __syncthreads();
    for (int rr = 0; rr < 4; ++rr) {
        int row = r + rr * 8;
        zT[(size_t)(b * T_ + t0 + row) * C_ + c0 + col] =
            __float2bfloat16(tile[col][row]);
    }
}

// ---------------------------------------------------------------- pack weight
// w[c][o][i] f32 -> wTb[j][c] bf16 with j = i*256 + o
__global__ __launch_bounds__(256) void pack_w(const float* __restrict__ w,
                                              bf16* __restrict__ wTb) {
    int gid = blockIdx.x * 256 + threadIdx.x;
    int j = gid >> 8, c = gid & 255;
    int o = j & 255, i = j >> 8;
    wTb[gid] = __float2bfloat16(w[(size_t)c * (C_ * PS) + o * PS + i]);
}

// ---------------------------------------------------------------- FUSED
// One block = (b, 64 consecutive s). zp is NEVER materialized in HBM.
//   Prologue: zT rows t in [s0-27, s0+47] (80 rows, 40KB) -> LDS via GLL
//     (XOR-swizzled source, vmcnt(0)+barrier right after: proven pattern).
//   Loop cs = 0..7 (32-channel output slices), NOT unrolled:
//     GEMM  : M=80 x N=384(12i x 32o) x K=256; A from LDS (swizzled
//             ds_read_b128), B = wTb rows via plain C++ loads (compiler-
//             managed waits; wTb is 1.5MB L2-resident). acc[5][3]/wave.
//     sync  : prior predict's smZ reads complete
//     EPI   : acc(+bias) -> smZ [80 rows][768B] bf16, XOR-swizzled granules
//     sync  : smZ published
//     PRED  : per wave 8 s-values: targets t8 gathered via plain loads
//             (L2/L3-resident zT), zf from smZ; 8 MFMA accumulate
//             oacc[it] (out[s][n][i]) across cs in registers.
//   Final masked f32x4 stores. No atomics, no raw-asm VGPR loads.
__global__ __launch_bounds__(512, 2) void fused_kernel(
    const bf16* __restrict__ zT, const bf16* __restrict__ wTb,
    const float* __restrict__ bias, const int* __restrict__ neg,
    float* __restrict__ out) {
    __shared__ __align__(16) char smem[103424];
    char* smA = smem;                         // [80][512B]  A tile (swz)
    char* smZ = smem + 40960;                 // [80][768B]  zp slice (swz)
    float* smBias = (float*)(smem + 102400);  // 256 f32

    const int tid = threadIdx.x;
    const int wid = tid >> 6, lane = tid & 63;
    const int ln15 = lane & 15, kg = lane >> 4;

    int raw = blockIdx.x;                     // grid 512 = 8 * 64 (bijective)
    int bid = (raw & 7) * 64 + (raw >> 3);
    const int b = bid >> 5, sblk = bid & 31;
    const int s0 = OFFS + sblk * 64;
    const int t_base = s0 - 27;

    if (tid < C_) smBias[tid] = bias[tid];

    // ---- A-tile stage: 80 rows, 5 GLL/wave, source-swizzled (g ^= row&7)
    {
        int g31 = lane & 31;
#pragma unroll
        for (int g = 0; g < 5; ++g) {
            int r2 = wid * 10 + g * 2;             // wave-uniform LDS base row
            int rt = r2 + (lane >> 5);             // per-lane source row
            int t = t_base + rt;
            t = t < 0 ? 0 : (t > T_ - 1 ? T_ - 1 : t);
            const char* src = (const char*)(zT + (size_t)(b * T_ + t) * C_) +
                              ((g31 ^ (rt & 7)) << 4);
            GLL(src, smA + r2 * 512);
        }
    }
    asm volatile("s_waitcnt vmcnt(0)" ::: "memory");
    __syncthreads();                          // A + bias published

    // ---- per-wave target row indices (8 s per wave)
    const int s_w = s0 + wid * 8;
    const int s_rd = s_w > T_ - 8 ? T_ - 8 : s_w;  // OOB-safe (clamped waves
    int srcrow[8];                                  //  are fully store-masked)
    if (lane == 0) {
#pragma unroll
        for (int it = 0; it < 8; ++it) srcrow[it] = b * T_ + s_rd + it;
    } else if (lane < 16) {
        const int* np = neg + b * (NNEG * T_) + (lane - 1) * T_ + s_rd;
        int4 n0 = *(const int4*)np;
        int4 n1 = *(const int4*)(np + 4);
        srcrow[0] = n0.x; srcrow[1] = n0.y; srcrow[2] = n0.z; srcrow[3] = n0.w;
        srcrow[4] = n1.x; srcrow[5] = n1.y; srcrow[6] = n1.z; srcrow[7] = n1.w;
    } else {
#pragma unroll
        for (int it = 0; it < 8; ++it) srcrow[it] = 0;
    }

    // ---- per-wave column metadata (N = 384 = 12i x 32o; wave owns 48 cols)
    const int wn = wid * 48;
    int wrow[3];                    // wTb row base: i*256 + o32
#pragma unroll
    for (int j = 0; j < 3; ++j) {
        int col = wn + j * 16 + ln15;
        wrow[j] = (col >> 5) * 256 + (col & 31);
    }
    int abase[5], a7[5];
#pragma unroll
    for (int m = 0; m < 5; ++m) {
        int r = m * 16 + ln15;
        abase[m] = r * 512;
        a7[m] = r & 7;
    }
    const int ii = ln15 < PS ? ln15 : 0;    // predict step (pad lanes dup 0)

    f32x4 oacc[8] = {};                     // out[s][n][i] partials, all cs

#pragma unroll 1
    for (int cs = 0; cs < 8; ++cs) {
        // -------- GEMM slice: K fully unrolled, compiler-scheduled loads
        f32x4 acc[5][3] = {};
#pragma unroll
        for (int k = 0; k < 8; ++k) {
            bf16x8 bfr[3];
#pragma unroll
            for (int j = 0; j < 3; ++j)
                bfr[j] = *(const bf16x8*)((const char*)wTb +
                          (((size_t)(wrow[j] + cs * 32)) << 9) +
                          (k << 6) + (kg << 4));
            bf16x8 af[5];
#pragma unroll
            for (int m = 0; m < 5; ++m)
                af[m] = *(const bf16x8*)(smA + abase[m] +
                                         (((k * 4 + kg) ^ a7[m]) << 4));
#pragma unroll
            for (int m = 0; m < 5; ++m)
#pragma unroll
                for (int j = 0; j < 3; ++j)
                    acc[m][j] = __builtin_amdgcn_mfma_f32_16x16x32_bf16(
                        af[m], bfr[j], acc[m][j], 0, 0, 0);
        }

        __syncthreads();   // prior predict's smZ reads complete (no-op cs=0)

        // -------- epilogue: acc(+bias) -> smZ bf16, swizzled granules
        {
            float bv0 = smBias[cs * 32 + ln15];
            float bv1 = smBias[cs * 32 + 16 + ln15];
#pragma unroll
            for (int m = 0; m < 5; ++m)
#pragma unroll
                for (int j = 0; j < 3; ++j) {
                    int col = wn + j * 16 + ln15;
                    float bvj = (((wid & 1) + j) & 1) ? bv1 : bv0;
#pragma unroll
                    for (int r = 0; r < 4; ++r) {
                        int row = m * 16 + kg * 4 + r;
                        int gz = (col >> 3) ^ (row & 7);
                        *(bf16*)(smZ + row * 768 + (gz << 4) +
                                 ((col & 7) << 1)) =
                            __float2bfloat16(acc[m][j][r] + bvj);
                    }
                }
        }

        __syncthreads();   // smZ published

        // -------- predict slice: plain gathered loads + 8 MFMA
        {
            bf16x8 t8[8], zf[8];
#pragma unroll
            for (int it = 0; it < 8; ++it) {
                int row = __shfl(srcrow[it], ln15);
                t8[it] = *(const bf16x8*)((const char*)zT +
                          ((size_t)row << 9) + (cs << 6) + (kg << 4));
                int rowP = wid * 8 + it + 11 - ii;
                zf[it] = *(const bf16x8*)(smZ + rowP * 768 +
                          (((ii * 4 + kg) ^ (rowP & 7)) << 4));
            }
#pragma unroll
            for (int it = 0; it < 8; ++it)
                oacc[it] = __builtin_amdgcn_mfma_f32_16x16x32_bf16(
                    t8[it], zf[it], oacc[it], 0, 0, 0);
        }
    }

    // ---- final store (masked)
    if (ln15 < PS) {
        int i = ln15;
        int bi = 256 * ((T_ - OFFS) * i - (i * (i - 1)) / 2);
#pragma unroll
        for (int it = 0; it < 8; ++it) {
            int s = s_w + it;
            if (s < T_ && i <= s - OFFS) {
                int t = s - OFFS - i;
                *(f32x4*)(out + bi + (t * B_ + b) * COPIES + kg * 4) = oacc[it];
            }
        }
    }
}

// ---------------------------------------------------------------- launch
extern "C" void kernel_launch(void* const* d_in, const int* in_sizes, int n_in,
                              void* d_out, int out_size, void* d_ws, size_t ws_size,
                              hipStream_t stream) {
    const float* z    = (const float*)d_in[0];
    const float* w    = (const float*)d_in[1];
    const float* bias = (const float*)d_in[2];
    const int*   neg  = (const int*)d_in[3];
    float* out = (float*)d_out;

    char* ws = (char*)d_ws;
    bf16* zT  = (bf16*)ws;                                   // 16777216 B
    bf16* wTb = (bf16*)(ws + (size_t)B_ * T_ * C_ * sizeof(bf16));

    transpose_z<<<dim3(T_ / 32, C_ / 32, B_), 256, 0, stream>>>(z, zT);
    pack_w<<<(C_ * PS * C_) / 256, 256, 0, stream>>>(w, wTb);
    fused_kernel<<<512, 512, 0, stream>>>(zT, wTb, bias, neg, out);
    hipMemsetAsync(out + NPRED, 0, NLAB * sizeof(float), stream);
}